// Round 2
// baseline (208.685 us; speedup 1.0000x reference)
//
#include <hip/hip_runtime.h>
#include <hip/hip_bf16.h>
#include <math.h>

// TopicRouter split in two streaming kernels:
//  A) router_logits: logits[B,8] = h @ gate_w^T + b.  HBM-bound (96 MB of h).
//     One wave per row-pair per iteration, software-prefetch depth 1 so every
//     wave keeps 6 KB of loads in flight during its compute phase.
//     Logits stored as one coalesced 64 B chunk per pair (no write amplification).
//  B) router_topk: per-thread top-2 + softmax over logits (1 MB read),
//     zero cross-lane ops, coalesced float2 stores.

constexpr int D  = 768;
constexpr int E  = 8;
constexpr int D4 = D / 4;          // 192 float4 per row
constexpr int BLOCK  = 256;        // 4 waves
constexpr int GRID_A = 512;        // 2048 waves -> 8 row-pairs per wave

__device__ __forceinline__ float dot4acc(float4 a, float4 b, float acc) {
    acc = fmaf(a.x, b.x, acc);
    acc = fmaf(a.y, b.y, acc);
    acc = fmaf(a.z, b.z, acc);
    acc = fmaf(a.w, b.w, acc);
    return acc;
}

// Reduce a[8] (per-expert partials) across 64 lanes.
// Returns: this lane's total for expert e = bitrev3(lane&7).
__device__ __forceinline__ float wave_reduce8(float a[8], int lane) {
    {   // xor 1: 8 -> 4 values
        const bool hi = lane & 1;
#pragma unroll
        for (int j = 0; j < 4; ++j) {
            float send = hi ? a[j] : a[j + 4];
            float recv = __shfl_xor(send, 1, 64);
            float keep = hi ? a[j + 4] : a[j];
            a[j] = keep + recv;
        }
    }
    {   // xor 2: 4 -> 2
        const bool hi = lane & 2;
#pragma unroll
        for (int j = 0; j < 2; ++j) {
            float send = hi ? a[j] : a[j + 2];
            float recv = __shfl_xor(send, 2, 64);
            float keep = hi ? a[j + 2] : a[j];
            a[j] = keep + recv;
        }
    }
    {   // xor 4: 2 -> 1
        const bool hi = lane & 4;
        float send = hi ? a[0] : a[1];
        float recv = __shfl_xor(send, 4, 64);
        float keep = hi ? a[1] : a[0];
        a[0] = keep + recv;
    }
    float v = a[0];
    v += __shfl_xor(v, 8, 64);
    v += __shfl_xor(v, 16, 64);
    v += __shfl_xor(v, 32, 64);
    return v;
}

__device__ __forceinline__ void load_pair(float4 dst[6], const float4* __restrict__ h4,
                                          int pair, int lane) {
    const float4* hp = h4 + (size_t)pair * (2 * D4) + lane;
#pragma unroll
    for (int c = 0; c < 3; ++c) dst[c]     = hp[c * 64];        // row 2p
#pragma unroll
    for (int c = 0; c < 3; ++c) dst[3 + c] = hp[D4 + c * 64];   // row 2p+1
}

__global__ __launch_bounds__(BLOCK, 4)
void router_logits_kernel(const float* __restrict__ h,
                          const float* __restrict__ gate_w,
                          const float* __restrict__ gate_b,
                          float* __restrict__ out_logits,
                          int B) {
    __shared__ float gate_s[E * D];

    const int tid = threadIdx.x;
    const float4* gw4 = (const float4*)gate_w;
    float4* gs4 = (float4*)gate_s;
#pragma unroll
    for (int i = tid; i < E * D4; i += BLOCK) gs4[i] = gw4[i];
    __syncthreads();

    const int lane   = tid & 63;
    const int wave   = tid >> 6;
    const int gwave  = blockIdx.x * (BLOCK / 64) + wave;
    const int nwaves = gridDim.x * (BLOCK / 64);

    const int l3 = lane & 7;
    const int e_lane = ((l3 & 1) << 2) | (l3 & 2) | ((l3 >> 2) & 1);  // bitrev3
    const float bias = gate_b[e_lane];

    const float4* h4 = (const float4*)h;
    const int npairs = B >> 1;

    int p = gwave;
    if (p >= npairs) return;

    float4 cv[6];
    load_pair(cv, h4, p, lane);      // prime the pipeline

    while (true) {
        const int pn = p + nwaves;
        const bool more = (pn < npairs);   // wave-uniform branch

        float4 nv[6];
        if (more) load_pair(nv, h4, pn, lane);   // prefetch: in flight all compute

        float acc0[E], acc1[E];
#pragma unroll
        for (int e = 0; e < E; ++e) { acc0[e] = 0.0f; acc1[e] = 0.0f; }

#pragma unroll
        for (int c = 0; c < 3; ++c) {
#pragma unroll
            for (int e = 0; e < E; ++e) {
                float4 g = gs4[e * D4 + c * 64 + lane];
                acc0[e] = dot4acc(cv[c],     g, acc0[e]);
                acc1[e] = dot4acc(cv[3 + c], g, acc1[e]);
            }
        }

        float va = wave_reduce8(acc0, lane) + bias;
        float vb = wave_reduce8(acc1, lane) + bias;

        // Lanes 0..15 write both rows' logits as one contiguous 64 B chunk:
        // addr = p*16 + (lane&8) + e_lane  (row 2p for octet 0, 2p+1 for octet 1)
        float v = (lane & 8) ? vb : va;
        if (lane < 16) out_logits[(size_t)p * 16 + (lane & 8) + e_lane] = v;

        if (!more) break;
#pragma unroll
        for (int i = 0; i < 6; ++i) cv[i] = nv[i];
        p = pn;
    }
}

__global__ __launch_bounds__(BLOCK)
void router_topk_kernel(const float* __restrict__ logits,
                        float* __restrict__ out_idx,
                        float* __restrict__ out_w,
                        int B) {
    const int t = blockIdx.x * BLOCK + threadIdx.x;
    if (t >= B) return;

    const float4* lp = (const float4*)(logits + (size_t)t * 8);
    float4 a = lp[0], b = lp[1];
    float l[8] = {a.x, a.y, a.z, a.w, b.x, b.y, b.z, b.w};

    // Stable top-2 (strict >): ties keep the lower expert index (lax.top_k).
    float v0 = l[0]; int i0 = 0;
    float v1 = -INFINITY; int i1 = -1;
#pragma unroll
    for (int e = 1; e < 8; ++e) {
        float x = l[e];
        bool gt0 = x > v0;
        bool gt1 = x > v1;
        float nv1 = gt0 ? v0 : (gt1 ? x : v1);
        int   ni1 = gt0 ? i0 : (gt1 ? e : i1);
        v1 = nv1; i1 = ni1;
        v0 = gt0 ? x : v0;
        i0 = gt0 ? e : i0;
    }
    float tt = expf(v1 - v0);
    float w0 = 1.0f / (1.0f + tt);
    float w1 = tt * w0;

    ((float2*)out_idx)[t] = make_float2((float)i0, (float)i1);
    ((float2*)out_w)[t]   = make_float2(w0, w1);
}

extern "C" void kernel_launch(void* const* d_in, const int* in_sizes, int n_in,
                              void* d_out, int out_size, void* d_ws, size_t ws_size,
                              hipStream_t stream) {
    const float* h      = (const float*)d_in[0];
    const float* gate_w = (const float*)d_in[1];
    const float* gate_b = (const float*)d_in[2];

    const int B = in_sizes[0] / D;   // 32768

    float* out        = (float*)d_out;
    float* out_idx    = out;                       // [B,2] indices as float
    float* out_w      = out + (size_t)B * 2;       // [B,2] weights
    float* out_logits = out + (size_t)B * 4;       // [B,8] logits

    router_logits_kernel<<<dim3(GRID_A), dim3(BLOCK), 0, stream>>>(
        h, gate_w, gate_b, out_logits, B);

    router_topk_kernel<<<dim3((B + BLOCK - 1) / BLOCK), dim3(BLOCK), 0, stream>>>(
        out_logits, out_idx, out_w, B);
}

// Round 3
// 148.059 us; speedup vs baseline: 1.4095x; 1.4095x over previous
//
#include <hip/hip_runtime.h>
#include <hip/hip_bf16.h>
#include <math.h>

// TopicRouter, two kernels:
//  A) router_logits: logits[B,8] = h @ gate_w^T + b. HBM-bound (96 MB of h).
//     Gate weights live in 96 VGPRs per lane (loop-invariant, no LDS at all).
//     One wave per row-pair, software-prefetch depth 1 held in registers —
//     __launch_bounds__(256,2) gives a 256-VGPR budget so nothing spills
//     (R2's (256,4) + LDS tile spilled the prefetch buffer: +96 MB scratch
//     writes to HBM).
//  B) router_topk: per-thread top-2 + softmax over logits (1 MB), coalesced.

constexpr int D  = 768;
constexpr int E  = 8;
constexpr int D4 = D / 4;          // 192 float4 per row
constexpr int BLOCK  = 256;        // 4 waves
constexpr int GRID_A = 512;        // 2048 waves -> 8 row-pairs per wave

__device__ __forceinline__ float dot4acc(float4 a, float4 b, float acc) {
    acc = fmaf(a.x, b.x, acc);
    acc = fmaf(a.y, b.y, acc);
    acc = fmaf(a.z, b.z, acc);
    acc = fmaf(a.w, b.w, acc);
    return acc;
}

// Reduce a[8] (per-expert partials) across 64 lanes.
// Returns: this lane's total for expert e = bitrev3(lane&7).
__device__ __forceinline__ float wave_reduce8(float a[8], int lane) {
    {   // xor 1: 8 -> 4 values
        const bool hi = lane & 1;
#pragma unroll
        for (int j = 0; j < 4; ++j) {
            float send = hi ? a[j] : a[j + 4];
            float recv = __shfl_xor(send, 1, 64);
            float keep = hi ? a[j + 4] : a[j];
            a[j] = keep + recv;
        }
    }
    {   // xor 2: 4 -> 2
        const bool hi = lane & 2;
#pragma unroll
        for (int j = 0; j < 2; ++j) {
            float send = hi ? a[j] : a[j + 2];
            float recv = __shfl_xor(send, 2, 64);
            float keep = hi ? a[j + 2] : a[j];
            a[j] = keep + recv;
        }
    }
    {   // xor 4: 2 -> 1
        const bool hi = lane & 4;
        float send = hi ? a[0] : a[1];
        float recv = __shfl_xor(send, 4, 64);
        float keep = hi ? a[1] : a[0];
        a[0] = keep + recv;
    }
    float v = a[0];
    v += __shfl_xor(v, 8, 64);
    v += __shfl_xor(v, 16, 64);
    v += __shfl_xor(v, 32, 64);
    return v;
}

__device__ __forceinline__ void load_pair(float4 dst[6], const float4* __restrict__ h4,
                                          int pair, int lane) {
    const float4* hp = h4 + (size_t)pair * (2 * D4) + lane;
#pragma unroll
    for (int c = 0; c < 3; ++c) dst[c]     = hp[c * 64];        // row 2p
#pragma unroll
    for (int c = 0; c < 3; ++c) dst[3 + c] = hp[D4 + c * 64];   // row 2p+1
}

__global__ __launch_bounds__(BLOCK, 2)
void router_logits_kernel(const float* __restrict__ h,
                          const float* __restrict__ gate_w,
                          const float* __restrict__ gate_b,
                          float* __restrict__ out_logits,
                          int B) {
    const int tid    = threadIdx.x;
    const int lane   = tid & 63;
    const int wave   = tid >> 6;
    const int gwave  = blockIdx.x * (BLOCK / 64) + wave;
    const int nwaves = gridDim.x * (BLOCK / 64);

    const int l3 = lane & 7;
    const int e_lane = ((l3 & 1) << 2) | (l3 & 2) | ((l3 >> 2) & 1);  // bitrev3
    const float bias = gate_b[e_lane];

    // Loop-invariant gate slice for this lane: 24 float4 = 96 VGPRs.
    // greg[e*3+c] = gate_w[e][4*lane + 256*c .. +3]
    const float4* gw4 = (const float4*)gate_w;
    float4 greg[24];
#pragma unroll
    for (int e = 0; e < E; ++e)
#pragma unroll
        for (int c = 0; c < 3; ++c)
            greg[e * 3 + c] = gw4[e * D4 + c * 64 + lane];

    const float4* h4 = (const float4*)h;
    const int npairs = B >> 1;

    int p = gwave;
    if (p >= npairs) return;

    float4 cv[6];
    load_pair(cv, h4, p, lane);      // prime the pipeline

    while (true) {
        const int pn = p + nwaves;
        const bool more = (pn < npairs);   // wave-uniform branch

        float4 nv[6];
        if (more) load_pair(nv, h4, pn, lane);   // in flight during compute

        float acc0[E], acc1[E];
#pragma unroll
        for (int e = 0; e < E; ++e) { acc0[e] = 0.0f; acc1[e] = 0.0f; }

#pragma unroll
        for (int c = 0; c < 3; ++c) {
#pragma unroll
            for (int e = 0; e < E; ++e) {
                float4 g = greg[e * 3 + c];
                acc0[e] = dot4acc(cv[c],     g, acc0[e]);
                acc1[e] = dot4acc(cv[3 + c], g, acc1[e]);
            }
        }

        float va = wave_reduce8(acc0, lane) + bias;
        float vb = wave_reduce8(acc1, lane) + bias;

        // Lanes 0..15 write both rows' logits as one contiguous 64 B chunk.
        float v = (lane & 8) ? vb : va;
        if (lane < 16) out_logits[(size_t)p * 16 + (lane & 8) + e_lane] = v;

        if (!more) break;
#pragma unroll
        for (int i = 0; i < 6; ++i) cv[i] = nv[i];
        p = pn;
    }
}

__global__ __launch_bounds__(BLOCK)
void router_topk_kernel(const float* __restrict__ logits,
                        float* __restrict__ out_idx,
                        float* __restrict__ out_w,
                        int B) {
    const int t = blockIdx.x * BLOCK + threadIdx.x;
    if (t >= B) return;

    const float4* lp = (const float4*)(logits + (size_t)t * 8);
    float4 a = lp[0], b = lp[1];
    float l[8] = {a.x, a.y, a.z, a.w, b.x, b.y, b.z, b.w};

    // Stable top-2 (strict >): ties keep the lower expert index (lax.top_k).
    float v0 = l[0]; int i0 = 0;
    float v1 = -INFINITY; int i1 = -1;
#pragma unroll
    for (int e = 1; e < 8; ++e) {
        float x = l[e];
        bool gt0 = x > v0;
        bool gt1 = x > v1;
        float nv1 = gt0 ? v0 : (gt1 ? x : v1);
        int   ni1 = gt0 ? i0 : (gt1 ? e : i1);
        v1 = nv1; i1 = ni1;
        v0 = gt0 ? x : v0;
        i0 = gt0 ? e : i0;
    }
    float tt = expf(v1 - v0);
    float w0 = 1.0f / (1.0f + tt);
    float w1 = tt * w0;

    ((float2*)out_idx)[t] = make_float2((float)i0, (float)i1);
    ((float2*)out_w)[t]   = make_float2(w0, w1);
}

extern "C" void kernel_launch(void* const* d_in, const int* in_sizes, int n_in,
                              void* d_out, int out_size, void* d_ws, size_t ws_size,
                              hipStream_t stream) {
    const float* h      = (const float*)d_in[0];
    const float* gate_w = (const float*)d_in[1];
    const float* gate_b = (const float*)d_in[2];

    const int B = in_sizes[0] / D;   // 32768

    float* out        = (float*)d_out;
    float* out_idx    = out;                       // [B,2] indices as float
    float* out_w      = out + (size_t)B * 2;       // [B,2] weights
    float* out_logits = out + (size_t)B * 4;       // [B,8] logits

    router_logits_kernel<<<dim3(GRID_A), dim3(BLOCK), 0, stream>>>(
        h, gate_w, gate_b, out_logits, B);

    router_topk_kernel<<<dim3((B + BLOCK - 1) / BLOCK), dim3(BLOCK), 0, stream>>>(
        out_logits, out_idx, out_w, B);
}